// Round 2
// baseline (262.246 us; speedup 1.0000x reference)
//
#include <hip/hip_runtime.h>
#include <hip/hip_bf16.h>

// B=16, T=2048, C=384, H=64. out = softmax((x Wq)(x Wk)^T / sqrt(C)) (x Wv)
// ws (bf16): Kb[32768*64] | Vt[16][64][2048] | Wt[6*192*64] | cnt (u32)
// R5: fused qkv+attn in ONE plain kernel with a MANUAL device-scope atomic
// grid barrier (hipLaunchCooperativeKernel is rejected by graph capture ->
// R4's kernel never ran). Deadlock-free by capacity: LDS 46080 B -> 3
// blocks/CU, __launch_bounds__(256,2) guarantees >=2 blocks/CU by VGPR,
// so all 512 blocks are co-resident. Counter memset'd in kernel_launch
// (ws is poisoned between iterations).
// Block j -> batch b=(j&7)+8*(j>>8), q-tile qt=(j>>3)&31 in BOTH phases:
//  - Q produced and consumed in the same block -> stays in LDS (no Qb).
//  - K/V of batch b written AND read by blocks on XCD b&7 -> L2-local.
// Phase 1: X double-buffered, W single-buffered (2 barriers/chunk).
// Phase 2: unchanged flash (no-max base-2 softmax, S^T via A=K B=Q, l via
// ones-MFMA) + s_setprio(1) around S and PV MFMA clusters (T5).

typedef __bf16 bf16;
typedef __attribute__((ext_vector_type(8))) __bf16 bf16x8;
typedef __attribute__((ext_vector_type(4))) __bf16 bf16x4;
typedef __attribute__((ext_vector_type(4))) float f32x4;

#define SCALE_LOG2E (0.051031036307982884f * 1.4426950408889634f)

// ---------------------------------------------------------------------------
// Kernel 0: pack W^T, Wt[ck][h][c'] (c = ck*64+c', h in [0,192) = Wq|Wk|Wv).
// ---------------------------------------------------------------------------
__global__ void pack_w(const float* __restrict__ Wq, const float* __restrict__ Wk,
                       const float* __restrict__ Wv, bf16* __restrict__ Wt) {
    int idx = blockIdx.x * 256 + threadIdx.x;      // 0..73727
    int cc = idx & 63;
    int hh = (idx >> 6) % 192;
    int ck = idx / 12288;
    const float* W = (hh < 64) ? Wq : (hh < 128 ? Wk : Wv);
    Wt[idx] = (bf16)W[(ck * 64 + cc) * 64 + (hh & 63)];
}

// ---------------------------------------------------------------------------
// Fused kernel: 512 blocks x 256 thr (4 waves), manual grid barrier.
// LDS layout (46080 B total):
//   phase 1: Xs0[64*72] | Xs1[64*72] | Ws[192*72]          (X dbuf, W single)
//   phase 2: Qs=Xs0 (persists Q) | KsA 2x[64*72] @9216 | VsA 2x[64*72] @27648
//            Om [64][68] f32 @9216 (epilogue)
// ---------------------------------------------------------------------------
__global__ __launch_bounds__(256, 2) void fused_qkv_attn(
    const float* __restrict__ x, const bf16* __restrict__ Wt,
    bf16* __restrict__ Kb, bf16* __restrict__ Vtg, float* __restrict__ out,
    unsigned* __restrict__ cnt)
{
    __shared__ __align__(16) char smem[46080];
    bf16* Xs0 = (bf16*)smem;                  // 64*72
    bf16* Xs1 = (bf16*)(smem + 9216);         // 64*72
    bf16* Ws  = (bf16*)(smem + 18432);        // 192*72

    const int tid = threadIdx.x;
    const int wv = tid >> 6, lane = tid & 63, quad = lane >> 4, l16 = lane & 15;
    const int srow = tid >> 2, scb = (tid & 3) * 16;

    // block -> (batch, q-tile): batch b lives on XCD b&7 for BOTH phases.
    const int j0 = blockIdx.x;
    const int b  = (j0 & 7) + 8 * (j0 >> 8);
    const int qt = (j0 >> 3) & 31;
    const int row0 = b * 2048 + qt * 64;

    // ---------------- phase 1: QKV projection for rows [row0, row0+64) ----
    f32x4 acc[12];
#pragma unroll
    for (int n = 0; n < 12; n++) acc[n] = (f32x4){0.f, 0.f, 0.f, 0.f};

    float4 xpre[4];
    bf16x8 wpre[6];
#pragma unroll
    for (int k = 0; k < 4; k++) {
        int g = tid + k * 256;
        xpre[k] = *(const float4*)(x + (long)(row0 + (g >> 4)) * 384 + (g & 15) * 4);
    }
#pragma unroll
    for (int k = 0; k < 6; k++)
        wpre[k] = *(const bf16x8*)(Wt + (tid + k * 256) * 8);

    for (int ck = 0; ck < 6; ck++) {
        bf16* Xc = (ck & 1) ? Xs1 : Xs0;
        // commit X chunk (other X buffer is the one still being read)
#pragma unroll
        for (int k = 0; k < 4; k++) {
            int g = tid + k * 256;
            float4 xv = xpre[k];
            *(bf16x4*)(&Xc[(g >> 4) * 72 + (g & 15) * 4]) =
                (bf16x4){(bf16)xv.x, (bf16)xv.y, (bf16)xv.z, (bf16)xv.w};
        }
        __syncthreads();      // bar1: prev chunk's Ws reads complete (W single-buf)
#pragma unroll
        for (int k = 0; k < 6; k++) {
            int g = tid + k * 256;
            *(bf16x8*)(&Ws[(g >> 3) * 72 + (g & 7) * 8]) = wpre[k];
        }
        if (ck < 5) {
#pragma unroll
            for (int k = 0; k < 4; k++) {
                int g = tid + k * 256;
                xpre[k] = *(const float4*)(x + (long)(row0 + (g >> 4)) * 384 +
                                           (ck + 1) * 64 + (g & 15) * 4);
            }
#pragma unroll
            for (int k = 0; k < 6; k++)
                wpre[k] = *(const bf16x8*)(Wt + (ck + 1) * 12288 + (tid + k * 256) * 8);
        }
        __syncthreads();      // bar2: staging visible
#pragma unroll
        for (int kh = 0; kh < 2; kh++) {
            bf16x8 a = *(bf16x8*)(&Xc[(wv * 16 + l16) * 72 + kh * 32 + quad * 8]);
#pragma unroll
            for (int n = 0; n < 12; n++) {
                bf16x8 bb = *(bf16x8*)(&Ws[(n * 16 + l16) * 72 + kh * 32 + quad * 8]);
                acc[n] = __builtin_amdgcn_mfma_f32_16x16x32_bf16(a, bb, acc[n], 0, 0, 0);
            }
        }
    }

    // phase-1 epilogue: Q (scaled) -> LDS only; K,V transposed -> global
    __syncthreads();
    const int drow = wv * 16 + quad * 4;
#pragma unroll
    for (int n = 0; n < 4; n++) {
#pragma unroll
        for (int r = 0; r < 4; r++) {
            Xs0[(drow + r) * 72 + n * 16 + l16] = (bf16)(acc[n][r] * SCALE_LOG2E);
            Xs1[(drow + r) * 72 + n * 16 + l16] = (bf16)acc[n + 4][r];
            Ws [(n * 16 + l16) * 72 + drow + r] = (bf16)acc[n + 8][r];
        }
    }
    __syncthreads();
#pragma unroll
    for (int i = 0; i < 2; i++) {
        *(bf16x8*)(Kb + (long)(row0 + srow) * 64 + scb + i * 8) =
            *(bf16x8*)(&Xs1[srow * 72 + scb + i * 8]);
        *(bf16x8*)(Vtg + (long)(b * 64 + srow) * 2048 + qt * 64 + scb + i * 8) =
            *(bf16x8*)(&Ws[srow * 72 + scb + i * 8]);
    }

    // ---------------- manual grid barrier (capture-safe) ------------------
    __threadfence();          // release: this thread's K/V stores device-visible
    __syncthreads();          // whole block released
    if (tid == 0) {
        __hip_atomic_fetch_add(cnt, 1u, __ATOMIC_RELEASE, __HIP_MEMORY_SCOPE_AGENT);
        while (__hip_atomic_load(cnt, __ATOMIC_ACQUIRE, __HIP_MEMORY_SCOPE_AGENT) < 512u)
            __builtin_amdgcn_s_sleep(2);
    }
    __syncthreads();          // block observes thread-0's acquire
    __threadfence();          // acquire: invalidate stale cached K/V

    // ---------------- phase 2: flash attention (Q already in LDS) ---------
    bf16* Qs  = Xs0;                          // 64*72, Ps overlays after hoist
    bf16* Ps  = Qs;
    bf16* KsA = (bf16*)(smem + 9216);         // 2 x 64*72
    bf16* VsA = (bf16*)(smem + 27648);        // 2 x 64*72, Vt[h][key]

    const bf16* Kg = Kb + (long)b * 2048 * 64;
    const bf16* Vg = Vtg + (long)b * 64 * 2048;

    // prefetch k-tile 0 (written pre-barrier on this XCD -> L2-local)
    bf16x8 kp[2], vp[2];
#pragma unroll
    for (int i = 0; i < 2; i++) {
        kp[i] = *(const bf16x8*)(Kg + (long)srow * 64 + scb + i * 8);
        vp[i] = *(const bf16x8*)(Vg + (long)srow * 2048 + scb + i * 8);
    }

    f32x4 o[4], ol;
#pragma unroll
    for (int n = 0; n < 4; n++) o[n] = (f32x4){0.f, 0.f, 0.f, 0.f};
    ol = (f32x4){0.f, 0.f, 0.f, 0.f};

    // hoist Q^T b-frags (loop-invariant); Ps overlay safe: first Ps write is
    // after barA of kt=0, which every wave reaches only after its hoist.
    bf16x8 qb[4][2];
#pragma unroll
    for (int nt = 0; nt < 4; nt++)
#pragma unroll
        for (int kh = 0; kh < 2; kh++)
            qb[nt][kh] = *(bf16x8*)(&Qs[(nt * 16 + l16) * 72 + kh * 32 + quad * 8]);

    const bf16 one = (bf16)1.0f;
    const bf16x8 ones = {one, one, one, one, one, one, one, one};

    for (int kt = 0; kt < 32; kt++) {
        bf16* Kc = KsA + (kt & 1) * 4608;
        bf16* Vc = VsA + (kt & 1) * 4608;
#pragma unroll
        for (int i = 0; i < 2; i++) {
            *(bf16x8*)(&Kc[srow * 72 + scb + i * 8]) = kp[i];
            *(bf16x8*)(&Vc[srow * 72 + scb + i * 8]) = vp[i];
        }
        if (kt < 31) {
#pragma unroll
            for (int i = 0; i < 2; i++) {
                kp[i] = *(const bf16x8*)(Kg + (long)((kt + 1) * 64 + srow) * 64 + scb + i * 8);
                vp[i] = *(const bf16x8*)(Vg + (long)srow * 2048 + (kt + 1) * 64 + scb + i * 8);
            }
        }
        __syncthreads();        // barA: staging visible; prev Ps reads done

        // S^T = K Q^T : this wave's key subtile (m-tile = wv), all 4 q-tiles
        f32x4 s[4];
#pragma unroll
        for (int nt = 0; nt < 4; nt++) s[nt] = (f32x4){0.f, 0.f, 0.f, 0.f};
        __builtin_amdgcn_s_setprio(1);
#pragma unroll
        for (int kh = 0; kh < 2; kh++) {
            bf16x8 ka = *(bf16x8*)(&Kc[(wv * 16 + l16) * 72 + kh * 32 + quad * 8]);
#pragma unroll
            for (int nt = 0; nt < 4; nt++)
                s[nt] = __builtin_amdgcn_mfma_f32_16x16x32_bf16(ka, qb[nt][kh], s[nt], 0, 0, 0);
        }
        __builtin_amdgcn_s_setprio(0);
        // p = exp2(s) (no max: bounded scores), pack 4 -> b64 store
#pragma unroll
        for (int nt = 0; nt < 4; nt++) {
            bf16x4 pp;
#pragma unroll
            for (int r = 0; r < 4; r++)
                pp[r] = (bf16)__builtin_amdgcn_exp2f(s[nt][r]);
            *(bf16x4*)(&Ps[(nt * 16 + l16) * 72 + wv * 16 + quad * 4]) = pp;
        }
        __syncthreads();        // barB: full P^T visible

        // O^T += V^T P^T : this wave's q subtile (n = wv), all 4 h-tiles + l
        __builtin_amdgcn_s_setprio(1);
#pragma unroll
        for (int kh = 0; kh < 2; kh++) {
            bf16x8 pb = *(bf16x8*)(&Ps[(wv * 16 + l16) * 72 + kh * 32 + quad * 8]);
#pragma unroll
            for (int mt = 0; mt < 4; mt++) {
                bf16x8 va = *(bf16x8*)(&Vc[(mt * 16 + l16) * 72 + kh * 32 + quad * 8]);
                o[mt] = __builtin_amdgcn_mfma_f32_16x16x32_bf16(va, pb, o[mt], 0, 0, 0);
            }
            ol = __builtin_amdgcn_mfma_f32_16x16x32_bf16(ones, pb, ol, 0, 0, 0);
        }
        __builtin_amdgcn_s_setprio(0);
    }

    // epilogue: every lane holds l(q) in ol[*]; normalize, transpose via LDS
    float inv = 1.0f / ol[0];
    __syncthreads();
    float* Om = (float*)(smem + 9216);        // [64][68] floats (17408 B)
#pragma unroll
    for (int mt = 0; mt < 4; mt++) {
        f32x4 ov;
#pragma unroll
        for (int r = 0; r < 4; r++) ov[r] = o[mt][r] * inv;
        *(f32x4*)(&Om[(wv * 16 + l16) * 68 + mt * 16 + quad * 4]) = ov;
    }
    __syncthreads();
    float* og = out + (long)(b * 2048 + qt * 64 + srow) * 64 + scb;
#pragma unroll
    for (int i = 0; i < 4; i++)
        *(float4*)(og + i * 4) = *(float4*)(&Om[srow * 68 + scb + i * 4]);
}

// ---------------------------------------------------------------------------
extern "C" void kernel_launch(void* const* d_in, const int* in_sizes, int n_in,
                              void* d_out, int out_size, void* d_ws, size_t ws_size,
                              hipStream_t stream) {
    const float* x  = (const float*)d_in[0];
    const float* Wq = (const float*)d_in[1];
    const float* Wk = (const float*)d_in[2];
    const float* Wv = (const float*)d_in[3];
    float* out = (float*)d_out;

    bf16* Kb  = (bf16*)d_ws;           // 32768*64
    bf16* Vtg = Kb + 2097152;          // [16][64][2048]
    bf16* Wt  = Vtg + 2097152;         // 6*192*64
    unsigned* cnt = (unsigned*)((char*)d_ws + 8 * 1024 * 1024 + 256 * 1024);

    // ws is poisoned between iterations: zero the barrier counter first.
    hipMemsetAsync(cnt, 0, 4, stream);

    pack_w<<<288, 256, 0, stream>>>(Wq, Wk, Wv, Wt);
    fused_qkv_attn<<<512, 256, 0, stream>>>(x, Wt, Kb, Vtg, out, cnt);
}

// Round 3
// 144.763 us; speedup vs baseline: 1.8116x; 1.8116x over previous
//
#include <hip/hip_runtime.h>
#include <hip/hip_bf16.h>

// B=16, T=2048, C=384, H=64. out = softmax((x Wq)(x Wk)^T / sqrt(C)) (x Wv)
// ws (bf16): Kb[32768*64] | Vt[16][64][2048] | Wt[6*192*64] | cnt[16 lines]
// R6: fused qkv+attn, ONE plain kernel, PER-BATCH producer/consumer flags.
// R2 post-mortem: grid-wide spin polled with ACQUIRE at agent scope -> each
// poll emits buffer_inv sc1 (full XCD-L2 invalidate) -> continuous L2
// invalidation storm starved phase 1 (MfmaUtil 5%, 185 us). Fix:
//  - poll RELAXED (global_load sc1, coherent, NO cache ops),
//  - ONE acquire fence per block after the spin,
//  - release via thread-0 fetch_add(RELEASE) (one wbl2/block; syncthreads
//    already drained all waves' stores to L2),
//  - 16 per-batch flags (own cacheline): consumers start attention as soon
//    as THEIR batch's 32 producer blocks are done -> phases pipeline.
// Deadlock-free: LDS 46080 B -> 3 blocks/CU capacity = 768 >= 512 grid
// (co-residency empirically proven by R2 passing).
// Block j -> batch b=(j&7)+8*(j>>8), q-tile qt=(j>>3)&31 in BOTH phases:
// Q stays in LDS (no Qb round-trip); K/V of batch b written AND read on
// XCD b&7 (L2-local, perf heuristic only -- fences carry correctness).
// Phase 1: X dbuf, W single-buffered. Phase 2: flash, no-max base-2
// softmax, S^T via A=K B=Q, l via ones-MFMA, setprio around MFMA clusters.

typedef __bf16 bf16;
typedef __attribute__((ext_vector_type(8))) __bf16 bf16x8;
typedef __attribute__((ext_vector_type(4))) __bf16 bf16x4;
typedef __attribute__((ext_vector_type(4))) float f32x4;

#define SCALE_LOG2E (0.051031036307982884f * 1.4426950408889634f)

// ---------------------------------------------------------------------------
// Kernel 0: pack W^T, Wt[ck][h][c'] (c = ck*64+c', h in [0,192) = Wq|Wk|Wv).
// ---------------------------------------------------------------------------
__global__ void pack_w(const float* __restrict__ Wq, const float* __restrict__ Wk,
                       const float* __restrict__ Wv, bf16* __restrict__ Wt) {
    int idx = blockIdx.x * 256 + threadIdx.x;      // 0..73727
    int cc = idx & 63;
    int hh = (idx >> 6) % 192;
    int ck = idx / 12288;
    const float* W = (hh < 64) ? Wq : (hh < 128 ? Wk : Wv);
    Wt[idx] = (bf16)W[(ck * 64 + cc) * 64 + (hh & 63)];
}

// ---------------------------------------------------------------------------
// Fused kernel: 512 blocks x 256 thr (4 waves), per-batch flag sync.
// LDS layout (46080 B total):
//   phase 1: Xs0[64*72] | Xs1[64*72] | Ws[192*72]          (X dbuf, W single)
//   phase 2: Qs=Xs0 (persists Q) | KsA 2x[64*72] @9216 | VsA 2x[64*72] @27648
//            Om [64][68] f32 @9216 (epilogue)
// ---------------------------------------------------------------------------
__global__ __launch_bounds__(256, 2) void fused_qkv_attn(
    const float* __restrict__ x, const bf16* __restrict__ Wt,
    bf16* __restrict__ Kb, bf16* __restrict__ Vtg, float* __restrict__ out,
    unsigned* __restrict__ cnt)
{
    __shared__ __align__(16) char smem[46080];
    bf16* Xs0 = (bf16*)smem;                  // 64*72
    bf16* Xs1 = (bf16*)(smem + 9216);         // 64*72
    bf16* Ws  = (bf16*)(smem + 18432);        // 192*72

    const int tid = threadIdx.x;
    const int wv = tid >> 6, lane = tid & 63, quad = lane >> 4, l16 = lane & 15;
    const int srow = tid >> 2, scb = (tid & 3) * 16;

    // block -> (batch, q-tile): batch b lives on XCD b&7 for BOTH phases.
    const int j0 = blockIdx.x;
    const int b  = (j0 & 7) + 8 * (j0 >> 8);
    const int qt = (j0 >> 3) & 31;
    const int row0 = b * 2048 + qt * 64;

    // ---------------- phase 1: QKV projection for rows [row0, row0+64) ----
    f32x4 acc[12];
#pragma unroll
    for (int n = 0; n < 12; n++) acc[n] = (f32x4){0.f, 0.f, 0.f, 0.f};

    float4 xpre[4];
    bf16x8 wpre[6];
#pragma unroll
    for (int k = 0; k < 4; k++) {
        int g = tid + k * 256;
        xpre[k] = *(const float4*)(x + (long)(row0 + (g >> 4)) * 384 + (g & 15) * 4);
    }
#pragma unroll
    for (int k = 0; k < 6; k++)
        wpre[k] = *(const bf16x8*)(Wt + (tid + k * 256) * 8);

    for (int ck = 0; ck < 6; ck++) {
        bf16* Xc = (ck & 1) ? Xs1 : Xs0;
        // commit X chunk (other X buffer is the one still being read)
#pragma unroll
        for (int k = 0; k < 4; k++) {
            int g = tid + k * 256;
            float4 xv = xpre[k];
            *(bf16x4*)(&Xc[(g >> 4) * 72 + (g & 15) * 4]) =
                (bf16x4){(bf16)xv.x, (bf16)xv.y, (bf16)xv.z, (bf16)xv.w};
        }
        __syncthreads();      // bar1: prev chunk's Ws reads complete (W single-buf)
#pragma unroll
        for (int k = 0; k < 6; k++) {
            int g = tid + k * 256;
            *(bf16x8*)(&Ws[(g >> 3) * 72 + (g & 7) * 8]) = wpre[k];
        }
        if (ck < 5) {
#pragma unroll
            for (int k = 0; k < 4; k++) {
                int g = tid + k * 256;
                xpre[k] = *(const float4*)(x + (long)(row0 + (g >> 4)) * 384 +
                                           (ck + 1) * 64 + (g & 15) * 4);
            }
#pragma unroll
            for (int k = 0; k < 6; k++)
                wpre[k] = *(const bf16x8*)(Wt + (ck + 1) * 12288 + (tid + k * 256) * 8);
        }
        __syncthreads();      // bar2: staging visible
#pragma unroll
        for (int kh = 0; kh < 2; kh++) {
            bf16x8 a = *(bf16x8*)(&Xc[(wv * 16 + l16) * 72 + kh * 32 + quad * 8]);
#pragma unroll
            for (int n = 0; n < 12; n++) {
                bf16x8 bb = *(bf16x8*)(&Ws[(n * 16 + l16) * 72 + kh * 32 + quad * 8]);
                acc[n] = __builtin_amdgcn_mfma_f32_16x16x32_bf16(a, bb, acc[n], 0, 0, 0);
            }
        }
    }

    // phase-1 epilogue: Q (scaled) -> LDS only; K,V transposed -> global
    __syncthreads();
    const int drow = wv * 16 + quad * 4;
#pragma unroll
    for (int n = 0; n < 4; n++) {
#pragma unroll
        for (int r = 0; r < 4; r++) {
            Xs0[(drow + r) * 72 + n * 16 + l16] = (bf16)(acc[n][r] * SCALE_LOG2E);
            Xs1[(drow + r) * 72 + n * 16 + l16] = (bf16)acc[n + 4][r];
            Ws [(n * 16 + l16) * 72 + drow + r] = (bf16)acc[n + 8][r];
        }
    }
    __syncthreads();
#pragma unroll
    for (int i = 0; i < 2; i++) {
        *(bf16x8*)(Kb + (long)(row0 + srow) * 64 + scb + i * 8) =
            *(bf16x8*)(&Xs1[srow * 72 + scb + i * 8]);
        *(bf16x8*)(Vtg + (long)(b * 64 + srow) * 2048 + qt * 64 + scb + i * 8) =
            *(bf16x8*)(&Ws[srow * 72 + scb + i * 8]);
    }

    // ---------------- per-batch producer/consumer flag (capture-safe) -----
    // syncthreads drains every wave's K/V stores to L2 (compiler emits
    // s_waitcnt vmcnt(0) before s_barrier). Thread-0's RELEASE fetch_add
    // emits ONE wbl2 (cache-wide) -> whole block's stores reach coherence.
    // Polls are RELAXED: plain coherent loads, no buffer_inv (R2 bug).
    // One ACQUIRE fence per block after the spin pairs with the releases.
    __syncthreads();
    if (tid == 0) {
        unsigned* flag = cnt + b * 32;   // one 128B line per batch
        __hip_atomic_fetch_add(flag, 1u, __ATOMIC_RELEASE, __HIP_MEMORY_SCOPE_AGENT);
        while (__hip_atomic_load(flag, __ATOMIC_RELAXED, __HIP_MEMORY_SCOPE_AGENT) < 32u)
            __builtin_amdgcn_s_sleep(4);
        __builtin_amdgcn_fence(__ATOMIC_ACQUIRE, "agent");
    }
    __syncthreads();          // block observes thread-0's acquire

    // ---------------- phase 2: flash attention (Q already in LDS) ---------
    bf16* Qs  = Xs0;                          // 64*72, Ps overlays after hoist
    bf16* Ps  = Qs;
    bf16* KsA = (bf16*)(smem + 9216);         // 2 x 64*72
    bf16* VsA = (bf16*)(smem + 27648);        // 2 x 64*72, Vt[h][key]

    const bf16* Kg = Kb + (long)b * 2048 * 64;
    const bf16* Vg = Vtg + (long)b * 64 * 2048;

    // prefetch k-tile 0 (produced on this XCD -> L2-local)
    bf16x8 kp[2], vp[2];
#pragma unroll
    for (int i = 0; i < 2; i++) {
        kp[i] = *(const bf16x8*)(Kg + (long)srow * 64 + scb + i * 8);
        vp[i] = *(const bf16x8*)(Vg + (long)srow * 2048 + scb + i * 8);
    }

    f32x4 o[4], ol;
#pragma unroll
    for (int n = 0; n < 4; n++) o[n] = (f32x4){0.f, 0.f, 0.f, 0.f};
    ol = (f32x4){0.f, 0.f, 0.f, 0.f};

    // hoist Q^T b-frags (loop-invariant); Ps overlay safe: first Ps write is
    // after barA of kt=0, which every wave reaches only after its hoist.
    bf16x8 qb[4][2];
#pragma unroll
    for (int nt = 0; nt < 4; nt++)
#pragma unroll
        for (int kh = 0; kh < 2; kh++)
            qb[nt][kh] = *(bf16x8*)(&Qs[(nt * 16 + l16) * 72 + kh * 32 + quad * 8]);

    const bf16 one = (bf16)1.0f;
    const bf16x8 ones = {one, one, one, one, one, one, one, one};

    for (int kt = 0; kt < 32; kt++) {
        bf16* Kc = KsA + (kt & 1) * 4608;
        bf16* Vc = VsA + (kt & 1) * 4608;
#pragma unroll
        for (int i = 0; i < 2; i++) {
            *(bf16x8*)(&Kc[srow * 72 + scb + i * 8]) = kp[i];
            *(bf16x8*)(&Vc[srow * 72 + scb + i * 8]) = vp[i];
        }
        if (kt < 31) {
#pragma unroll
            for (int i = 0; i < 2; i++) {
                kp[i] = *(const bf16x8*)(Kg + (long)((kt + 1) * 64 + srow) * 64 + scb + i * 8);
                vp[i] = *(const bf16x8*)(Vg + (long)srow * 2048 + (kt + 1) * 64 + scb + i * 8);
            }
        }
        __syncthreads();        // barA: staging visible; prev Ps reads done

        // S^T = K Q^T : this wave's key subtile (m-tile = wv), all 4 q-tiles
        f32x4 s[4];
#pragma unroll
        for (int nt = 0; nt < 4; nt++) s[nt] = (f32x4){0.f, 0.f, 0.f, 0.f};
        __builtin_amdgcn_s_setprio(1);
#pragma unroll
        for (int kh = 0; kh < 2; kh++) {
            bf16x8 ka = *(bf16x8*)(&Kc[(wv * 16 + l16) * 72 + kh * 32 + quad * 8]);
#pragma unroll
            for (int nt = 0; nt < 4; nt++)
                s[nt] = __builtin_amdgcn_mfma_f32_16x16x32_bf16(ka, qb[nt][kh], s[nt], 0, 0, 0);
        }
        __builtin_amdgcn_s_setprio(0);
        // p = exp2(s) (no max: bounded scores), pack 4 -> b64 store
#pragma unroll
        for (int nt = 0; nt < 4; nt++) {
            bf16x4 pp;
#pragma unroll
            for (int r = 0; r < 4; r++)
                pp[r] = (bf16)__builtin_amdgcn_exp2f(s[nt][r]);
            *(bf16x4*)(&Ps[(nt * 16 + l16) * 72 + wv * 16 + quad * 4]) = pp;
        }
        __syncthreads();        // barB: full P^T visible

        // O^T += V^T P^T : this wave's q subtile (n = wv), all 4 h-tiles + l
        __builtin_amdgcn_s_setprio(1);
#pragma unroll
        for (int kh = 0; kh < 2; kh++) {
            bf16x8 pb = *(bf16x8*)(&Ps[(wv * 16 + l16) * 72 + kh * 32 + quad * 8]);
#pragma unroll
            for (int mt = 0; mt < 4; mt++) {
                bf16x8 va = *(bf16x8*)(&Vc[(mt * 16 + l16) * 72 + kh * 32 + quad * 8]);
                o[mt] = __builtin_amdgcn_mfma_f32_16x16x32_bf16(va, pb, o[mt], 0, 0, 0);
            }
            ol = __builtin_amdgcn_mfma_f32_16x16x32_bf16(ones, pb, ol, 0, 0, 0);
        }
        __builtin_amdgcn_s_setprio(0);
    }

    // epilogue: every lane holds l(q) in ol[*]; normalize, transpose via LDS
    float inv = 1.0f / ol[0];
    __syncthreads();
    float* Om = (float*)(smem + 9216);        // [64][68] floats (17408 B)
#pragma unroll
    for (int mt = 0; mt < 4; mt++) {
        f32x4 ov;
#pragma unroll
        for (int r = 0; r < 4; r++) ov[r] = o[mt][r] * inv;
        *(f32x4*)(&Om[(wv * 16 + l16) * 68 + mt * 16 + quad * 4]) = ov;
    }
    __syncthreads();
    float* og = out + (long)(b * 2048 + qt * 64 + srow) * 64 + scb;
#pragma unroll
    for (int i = 0; i < 4; i++)
        *(float4*)(og + i * 4) = *(float4*)(&Om[srow * 68 + scb + i * 4]);
}

// ---------------------------------------------------------------------------
extern "C" void kernel_launch(void* const* d_in, const int* in_sizes, int n_in,
                              void* d_out, int out_size, void* d_ws, size_t ws_size,
                              hipStream_t stream) {
    const float* x  = (const float*)d_in[0];
    const float* Wq = (const float*)d_in[1];
    const float* Wk = (const float*)d_in[2];
    const float* Wv = (const float*)d_in[3];
    float* out = (float*)d_out;

    bf16* Kb  = (bf16*)d_ws;           // 32768*64
    bf16* Vtg = Kb + 2097152;          // [16][64][2048]
    bf16* Wt  = Vtg + 2097152;         // 6*192*64
    unsigned* cnt = (unsigned*)((char*)d_ws + 8 * 1024 * 1024 + 256 * 1024);

    // ws is poisoned between iterations: zero the 16 per-batch flags first.
    hipMemsetAsync(cnt, 0, 16 * 32 * sizeof(unsigned), stream);

    pack_w<<<288, 256, 0, stream>>>(Wq, Wk, Wv, Wt);
    fused_qkv_attn<<<512, 256, 0, stream>>>(x, Wt, Kb, Vtg, out, cnt);
}

// Round 4
// 130.328 us; speedup vs baseline: 2.0122x; 1.1108x over previous
//
#include <hip/hip_runtime.h>
#include <hip/hip_bf16.h>

// B=16, T=2048, C=384, H=64. out = softmax((x Wq)(x Wk)^T / sqrt(C)) (x Wv)
// ws (bf16): Qb[32768*64] | Kb[32768*64] | Vt[16][64][2048] | Wt[6*192*64]
// R7: revert to the proven 3-kernel structure (fusion was EV-negative: the
// per-batch wait + degraded phase-1 cost more than the saved launch+Qb).
// flash_attn rescheduled: PV lags S by one iteration -> ONE barrier per
// k-iteration (was 2). Ps ping-pong (+9216 B LDS, 55296 total, still 2
// blocks/CU). S[kt] and PV[kt-1] are independent inside a barrier region,
// so MFMA/exp2/LDS overlap instead of serializing.

typedef __bf16 bf16;
typedef __attribute__((ext_vector_type(8))) __bf16 bf16x8;
typedef __attribute__((ext_vector_type(4))) __bf16 bf16x4;
typedef __attribute__((ext_vector_type(4))) float f32x4;

#define SCALE_LOG2E (0.051031036307982884f * 1.4426950408889634f)

// ---------------------------------------------------------------------------
// Kernel 0: pack W^T, Wt[ck][h][c'] (c = ck*64+c', h in [0,192) = Wq|Wk|Wv).
// ---------------------------------------------------------------------------
__global__ void pack_w(const float* __restrict__ Wq, const float* __restrict__ Wk,
                       const float* __restrict__ Wv, bf16* __restrict__ Wt) {
    int idx = blockIdx.x * 256 + threadIdx.x;      // 0..73727
    int cc = idx & 63;
    int hh = (idx >> 6) % 192;
    int ck = idx / 12288;
    const float* W = (hh < 64) ? Wq : (hh < 128 ? Wk : Wv);
    Wt[idx] = (bf16)W[(ck * 64 + cc) * 64 + (hh & 63)];
}

// ---------------------------------------------------------------------------
// Kernel 1: QKV projection (unchanged from the 131 us baseline).
// ---------------------------------------------------------------------------
__global__ __launch_bounds__(256) void qkv_proj(const float* __restrict__ x,
                                                const bf16* __restrict__ Wt,
                                                bf16* __restrict__ Qb,
                                                bf16* __restrict__ Kb,
                                                bf16* __restrict__ Vtg) {
    __shared__ __align__(16) bf16 Xs[2][64 * 72];
    __shared__ __align__(16) bf16 Ws[2][192 * 72];

    const int tid = threadIdx.x;
    const int wv = tid >> 6, lane = tid & 63, quad = lane >> 4, l16 = lane & 15;
    const int row0 = blockIdx.x * 64;

    f32x4 acc[12];
#pragma unroll
    for (int n = 0; n < 12; n++) acc[n] = (f32x4){0.f, 0.f, 0.f, 0.f};

    float4 xpre[4];
    bf16x8 wpre[6];
#pragma unroll
    for (int k = 0; k < 4; k++) {
        int g = tid + k * 256;
        xpre[k] = *(const float4*)(x + (long)(row0 + (g >> 4)) * 384 + (g & 15) * 4);
    }
#pragma unroll
    for (int k = 0; k < 6; k++)
        wpre[k] = *(const bf16x8*)(Wt + (tid + k * 256) * 8);

    for (int ck = 0; ck < 6; ck++) {
        bf16* Xc = Xs[ck & 1];
        bf16* Wc = Ws[ck & 1];
#pragma unroll
        for (int k = 0; k < 4; k++) {
            int g = tid + k * 256;
            float4 xv = xpre[k];
            *(bf16x4*)(&Xc[(g >> 4) * 72 + (g & 15) * 4]) =
                (bf16x4){(bf16)xv.x, (bf16)xv.y, (bf16)xv.z, (bf16)xv.w};
        }
#pragma unroll
        for (int k = 0; k < 6; k++) {
            int g = tid + k * 256;
            *(bf16x8*)(&Wc[(g >> 3) * 72 + (g & 7) * 8]) = wpre[k];
        }
        if (ck < 5) {
#pragma unroll
            for (int k = 0; k < 4; k++) {
                int g = tid + k * 256;
                xpre[k] = *(const float4*)(x + (long)(row0 + (g >> 4)) * 384 +
                                           (ck + 1) * 64 + (g & 15) * 4);
            }
#pragma unroll
            for (int k = 0; k < 6; k++)
                wpre[k] = *(const bf16x8*)(Wt + (ck + 1) * 12288 + (tid + k * 256) * 8);
        }
        __syncthreads();
#pragma unroll
        for (int kh = 0; kh < 2; kh++) {
            bf16x8 a = *(bf16x8*)(&Xc[(wv * 16 + l16) * 72 + kh * 32 + quad * 8]);
#pragma unroll
            for (int n = 0; n < 12; n++) {
                bf16x8 b = *(bf16x8*)(&Wc[(n * 16 + l16) * 72 + kh * 32 + quad * 8]);
                acc[n] = __builtin_amdgcn_mfma_f32_16x16x32_bf16(a, b, acc[n], 0, 0, 0);
            }
        }
    }

    __syncthreads();
    const int drow = wv * 16 + quad * 4;
#pragma unroll
    for (int n = 0; n < 4; n++) {
#pragma unroll
        for (int r = 0; r < 4; r++) {
            Xs[0][(drow + r) * 72 + n * 16 + l16] = (bf16)(acc[n][r] * SCALE_LOG2E);
            Xs[1][(drow + r) * 72 + n * 16 + l16] = (bf16)acc[n + 4][r];
            Ws[0][(n * 16 + l16) * 72 + drow + r] = (bf16)acc[n + 8][r];
        }
    }
    __syncthreads();
    const int b = row0 >> 11, t0 = row0 & 2047;
    const int srow = tid >> 2, scb = (tid & 3) * 16;
#pragma unroll
    for (int i = 0; i < 2; i++) {
        *(bf16x8*)(Qb + (long)(row0 + srow) * 64 + scb + i * 8) =
            *(bf16x8*)(&Xs[0][srow * 72 + scb + i * 8]);
        *(bf16x8*)(Kb + (long)(row0 + srow) * 64 + scb + i * 8) =
            *(bf16x8*)(&Xs[1][srow * 72 + scb + i * 8]);
        *(bf16x8*)(Vtg + (long)(b * 64 + srow) * 2048 + t0 + scb + i * 8) =
            *(bf16x8*)(&Ws[0][srow * 72 + scb + i * 8]);
    }
}

// ---------------------------------------------------------------------------
// Kernel 2: flash attention, 512 blocks x 256 thr (4 waves), 32 k-iters.
// ONE barrier per iteration: PV lags S by one iteration.
// LDS (55296 B): Ps0=Qs @0 (9216) | KsA 2x4608e @9216 | VsA 2x4608e @27648 |
//                Ps1 @46080 (9216). Om [64][68] f32 overlays @9216 (epilogue).
// Parity audit (all write->cross-wave-read pairs barrier-separated):
//   K: commit [kt+1 -> (kt+1)&1], S reads [kt&1]          (opposite)
//   V: commit [kt   -> kt&1],     PV reads [(kt-1)&1]     (opposite)
//   Ps: write [kt   -> kt&1],     PV reads [(kt-1)&1]     (opposite)
// ---------------------------------------------------------------------------
__global__ __launch_bounds__(256) void flash_attn(const bf16* __restrict__ Qb,
                                                  const bf16* __restrict__ Kb,
                                                  const bf16* __restrict__ Vtg,
                                                  float* __restrict__ out) {
    __shared__ __align__(16) char smem[55296];
    bf16* Qs  = (bf16*)smem;                  // 64*72; Ps0 overlays after hoist
    bf16* Ps0 = Qs;
    bf16* KsA = (bf16*)(smem + 9216);         // 2 x 64*72
    bf16* VsA = (bf16*)(smem + 27648);        // 2 x 64*72, Vt[h][key]
    bf16* Ps1 = (bf16*)(smem + 46080);        // 64*72

    const int tid = threadIdx.x;
    const int wv = tid >> 6, lane = tid & 63, quad = lane >> 4, l16 = lane & 15;
    // XCD-aware swizzle: keep a batch's K/V resident in one XCD's L2.
    const int i0 = blockIdx.x;
    const int b = (i0 & 7) + 8 * ((i0 >> 3) >> 5);
    const int qt = (i0 >> 3) & 31;

    const bf16* Qg = Qb + (long)(b * 2048 + qt * 64) * 64;
    const bf16* Kg = Kb + (long)b * 2048 * 64;
    const bf16* Vg = Vtg + (long)b * 64 * 2048;

    const int srow = tid >> 2, scb = (tid & 3) * 16;
    // stage Q tile [64][64]
    *(bf16x8*)(&Qs[srow * 72 + scb])     = *(const bf16x8*)(Qg + srow * 64 + scb);
    *(bf16x8*)(&Qs[srow * 72 + scb + 8]) = *(const bf16x8*)(Qg + srow * 64 + scb + 8);

    // prologue loads: K[0] (commit now), K[1] and V[0] (regs for kt=0)
    bf16x8 k0[2], kp[2], vp[2];
#pragma unroll
    for (int i = 0; i < 2; i++) {
        k0[i] = *(const bf16x8*)(Kg + (long)srow * 64 + scb + i * 8);
        kp[i] = *(const bf16x8*)(Kg + (long)(64 + srow) * 64 + scb + i * 8);
        vp[i] = *(const bf16x8*)(Vg + (long)srow * 2048 + scb + i * 8);
    }
#pragma unroll
    for (int i = 0; i < 2; i++)
        *(bf16x8*)(&KsA[srow * 72 + scb + i * 8]) = k0[i];

    f32x4 o[4], ol;
#pragma unroll
    for (int n = 0; n < 4; n++) o[n] = (f32x4){0.f, 0.f, 0.f, 0.f};
    ol = (f32x4){0.f, 0.f, 0.f, 0.f};

    __syncthreads();            // Qs + K[0] staged
    // hoist Q^T b-frags (loop-invariant)
    bf16x8 qb[4][2];
#pragma unroll
    for (int nt = 0; nt < 4; nt++)
#pragma unroll
        for (int kh = 0; kh < 2; kh++)
            qb[nt][kh] = *(bf16x8*)(&Qs[(nt * 16 + l16) * 72 + kh * 32 + quad * 8]);
    __syncthreads();            // all waves hoisted before Ps0 (=Qs) writes

    const bf16 one = (bf16)1.0f;
    const bf16x8 ones = {one, one, one, one, one, one, one, one};

#pragma unroll 2
    for (int kt = 0; kt < 32; kt++) {
        bf16* Kc = KsA + (kt & 1) * 4608;            // S source: K[kt]
        bf16* Kn = KsA + ((kt + 1) & 1) * 4608;      // commit K[kt+1]
        bf16* Vn = VsA + (kt & 1) * 4608;            // commit V[kt]
        bf16* Vp = VsA + ((kt + 1) & 1) * 4608;      // PV source: V[kt-1]
        bf16* Pw = (kt & 1) ? Ps1 : Ps0;             // write Ps[kt]
        bf16* Pr = (kt & 1) ? Ps0 : Ps1;             // read  Ps[kt-1]

        // commit prefetched tiles (regions not read this iteration)
        if (kt < 31) {
#pragma unroll
            for (int i = 0; i < 2; i++)
                *(bf16x8*)(&Kn[srow * 72 + scb + i * 8]) = kp[i];
        }
#pragma unroll
        for (int i = 0; i < 2; i++)
            *(bf16x8*)(&Vn[srow * 72 + scb + i * 8]) = vp[i];
        // issue next prefetches
        if (kt < 30) {
#pragma unroll
            for (int i = 0; i < 2; i++)
                kp[i] = *(const bf16x8*)(Kg + (long)((kt + 2) * 64 + srow) * 64 + scb + i * 8);
        }
        if (kt < 31) {
#pragma unroll
            for (int i = 0; i < 2; i++)
                vp[i] = *(const bf16x8*)(Vg + (long)srow * 2048 + (kt + 1) * 64 + scb + i * 8);
        }

        // S^T[kt] = K Q^T : wave's key subtile (m=wv), all 4 q-tiles
        f32x4 s[4];
#pragma unroll
        for (int nt = 0; nt < 4; nt++) s[nt] = (f32x4){0.f, 0.f, 0.f, 0.f};
#pragma unroll
        for (int kh = 0; kh < 2; kh++) {
            bf16x8 ka = *(bf16x8*)(&Kc[(wv * 16 + l16) * 72 + kh * 32 + quad * 8]);
#pragma unroll
            for (int nt = 0; nt < 4; nt++)
                s[nt] = __builtin_amdgcn_mfma_f32_16x16x32_bf16(ka, qb[nt][kh], s[nt], 0, 0, 0);
        }
        // p = exp2(s), pack 4 -> b64 store into Ps[kt]
#pragma unroll
        for (int nt = 0; nt < 4; nt++) {
            bf16x4 pp;
#pragma unroll
            for (int r = 0; r < 4; r++)
                pp[r] = (bf16)__builtin_amdgcn_exp2f(s[nt][r]);
            *(bf16x4*)(&Pw[(nt * 16 + l16) * 72 + wv * 16 + quad * 4]) = pp;
        }

        // O^T += V[kt-1]^T Ps[kt-1] : wave's q subtile (n=wv), 4 h-tiles + l
        if (kt) {
#pragma unroll
            for (int kh = 0; kh < 2; kh++) {
                bf16x8 pb = *(bf16x8*)(&Pr[(wv * 16 + l16) * 72 + kh * 32 + quad * 8]);
#pragma unroll
                for (int mt = 0; mt < 4; mt++) {
                    bf16x8 va = *(bf16x8*)(&Vp[(mt * 16 + l16) * 72 + kh * 32 + quad * 8]);
                    o[mt] = __builtin_amdgcn_mfma_f32_16x16x32_bf16(va, pb, o[mt], 0, 0, 0);
                }
                ol = __builtin_amdgcn_mfma_f32_16x16x32_bf16(ones, pb, ol, 0, 0, 0);
            }
        }
        __syncthreads();        // single barrier: publishes K[kt+1],V[kt],Ps[kt]
    }

    // peeled PV[31]: Ps[31] in Ps1, V[31] in VsA[1] (published by last barrier)
    {
        bf16* Pr = Ps1;
        bf16* Vp = VsA + 4608;
#pragma unroll
        for (int kh = 0; kh < 2; kh++) {
            bf16x8 pb = *(bf16x8*)(&Pr[(wv * 16 + l16) * 72 + kh * 32 + quad * 8]);
#pragma unroll
            for (int mt = 0; mt < 4; mt++) {
                bf16x8 va = *(bf16x8*)(&Vp[(mt * 16 + l16) * 72 + kh * 32 + quad * 8]);
                o[mt] = __builtin_amdgcn_mfma_f32_16x16x32_bf16(va, pb, o[mt], 0, 0, 0);
            }
            ol = __builtin_amdgcn_mfma_f32_16x16x32_bf16(ones, pb, ol, 0, 0, 0);
        }
    }

    // epilogue: every lane holds l(q) in ol[*]; normalize, transpose via LDS
    float inv = 1.0f / ol[0];
    __syncthreads();
    float* Om = (float*)(smem + 9216);        // [64][68] floats (17408 B)
#pragma unroll
    for (int mt = 0; mt < 4; mt++) {
        f32x4 ov;
#pragma unroll
        for (int r = 0; r < 4; r++) ov[r] = o[mt][r] * inv;
        *(f32x4*)(&Om[(wv * 16 + l16) * 68 + mt * 16 + quad * 4]) = ov;
    }
    __syncthreads();
    float* og = out + (long)(b * 2048 + qt * 64 + srow) * 64 + scb;
#pragma unroll
    for (int j = 0; j < 4; j++)
        *(float4*)(og + j * 4) = *(float4*)(&Om[srow * 68 + scb + j * 4]);
}

// ---------------------------------------------------------------------------
extern "C" void kernel_launch(void* const* d_in, const int* in_sizes, int n_in,
                              void* d_out, int out_size, void* d_ws, size_t ws_size,
                              hipStream_t stream) {
    const float* x  = (const float*)d_in[0];
    const float* Wq = (const float*)d_in[1];
    const float* Wk = (const float*)d_in[2];
    const float* Wv = (const float*)d_in[3];
    float* out = (float*)d_out;

    bf16* Qb  = (bf16*)d_ws;           // 32768*64
    bf16* Kb  = Qb + 2097152;
    bf16* Vtg = Kb + 2097152;          // [16][64][2048]
    bf16* Wt  = Vtg + 2097152;         // 6*192*64

    pack_w<<<288, 256, 0, stream>>>(Wq, Wk, Wv, Wt);
    qkv_proj<<<512, 256, 0, stream>>>(x, Wt, Qb, Kb, Vtg);
    flash_attn<<<512, 256, 0, stream>>>(Qb, Kb, Vtg, out);
}

// Round 5
// 125.415 us; speedup vs baseline: 2.0910x; 1.0392x over previous
//
#include <hip/hip_runtime.h>
#include <hip/hip_bf16.h>

// B=16, T=2048, C=384, H=64. out = softmax((x Wq)(x Wk)^T / sqrt(C)) (x Wv)
// ws (bf16): Qb[32768*64] | Kb[32768*64] | Vt[16][64][2048] | Wt[6*192*64]
// R8: flash LDS re-layout. Stride-72 pad gave a 4-bank row step -> every
// b128 fragment read ~8-way bank-aliased (R3 profile: 5.6M conflict cycles
// ~ up to 9 us/CU tax). Replace pad with T2 XOR swizzle: stride 64 (128 B
// rows), byte ^= ((row&7)<<4). All 16-row fragment accesses now hit 8
// distinct 16B slots per 8-row group = 2 lanes/bank (free). LDS 55296 ->
// 49152 B. Keeps R7's single-barrier PV-lags-S pipeline. qkv/pack unchanged.

typedef __bf16 bf16;
typedef __attribute__((ext_vector_type(8))) __bf16 bf16x8;
typedef __attribute__((ext_vector_type(4))) __bf16 bf16x4;
typedef __attribute__((ext_vector_type(4))) float f32x4;

#define SCALE_LOG2E (0.051031036307982884f * 1.4426950408889634f)

// swizzled element pointer into a [64][64] bf16 tile (128 B rows):
// byte = row*128 + (cbyte ^ ((row&7)<<4)); bijective, keeps 16B/8B alignment.
__device__ __forceinline__ bf16* tp(bf16* base, int row, int cbyte) {
    return (bf16*)((char*)base + row * 128 + (cbyte ^ ((row & 7) << 4)));
}
__device__ __forceinline__ const bf16* tpc(const bf16* base, int row, int cbyte) {
    return (const bf16*)((const char*)base + row * 128 + (cbyte ^ ((row & 7) << 4)));
}

// ---------------------------------------------------------------------------
// Kernel 0: pack W^T, Wt[ck][h][c'] (c = ck*64+c', h in [0,192) = Wq|Wk|Wv).
// ---------------------------------------------------------------------------
__global__ void pack_w(const float* __restrict__ Wq, const float* __restrict__ Wk,
                       const float* __restrict__ Wv, bf16* __restrict__ Wt) {
    int idx = blockIdx.x * 256 + threadIdx.x;      // 0..73727
    int cc = idx & 63;
    int hh = (idx >> 6) % 192;
    int ck = idx / 12288;
    const float* W = (hh < 64) ? Wq : (hh < 128 ? Wk : Wv);
    Wt[idx] = (bf16)W[(ck * 64 + cc) * 64 + (hh & 63)];
}

// ---------------------------------------------------------------------------
// Kernel 1: QKV projection (unchanged from the 131 us baseline).
// ---------------------------------------------------------------------------
__global__ __launch_bounds__(256) void qkv_proj(const float* __restrict__ x,
                                                const bf16* __restrict__ Wt,
                                                bf16* __restrict__ Qb,
                                                bf16* __restrict__ Kb,
                                                bf16* __restrict__ Vtg) {
    __shared__ __align__(16) bf16 Xs[2][64 * 72];
    __shared__ __align__(16) bf16 Ws[2][192 * 72];

    const int tid = threadIdx.x;
    const int wv = tid >> 6, lane = tid & 63, quad = lane >> 4, l16 = lane & 15;
    const int row0 = blockIdx.x * 64;

    f32x4 acc[12];
#pragma unroll
    for (int n = 0; n < 12; n++) acc[n] = (f32x4){0.f, 0.f, 0.f, 0.f};

    float4 xpre[4];
    bf16x8 wpre[6];
#pragma unroll
    for (int k = 0; k < 4; k++) {
        int g = tid + k * 256;
        xpre[k] = *(const float4*)(x + (long)(row0 + (g >> 4)) * 384 + (g & 15) * 4);
    }
#pragma unroll
    for (int k = 0; k < 6; k++)
        wpre[k] = *(const bf16x8*)(Wt + (tid + k * 256) * 8);

    for (int ck = 0; ck < 6; ck++) {
        bf16* Xc = Xs[ck & 1];
        bf16* Wc = Ws[ck & 1];
#pragma unroll
        for (int k = 0; k < 4; k++) {
            int g = tid + k * 256;
            float4 xv = xpre[k];
            *(bf16x4*)(&Xc[(g >> 4) * 72 + (g & 15) * 4]) =
                (bf16x4){(bf16)xv.x, (bf16)xv.y, (bf16)xv.z, (bf16)xv.w};
        }
#pragma unroll
        for (int k = 0; k < 6; k++) {
            int g = tid + k * 256;
            *(bf16x8*)(&Wc[(g >> 3) * 72 + (g & 7) * 8]) = wpre[k];
        }
        if (ck < 5) {
#pragma unroll
            for (int k = 0; k < 4; k++) {
                int g = tid + k * 256;
                xpre[k] = *(const float4*)(x + (long)(row0 + (g >> 4)) * 384 +
                                           (ck + 1) * 64 + (g & 15) * 4);
            }
#pragma unroll
            for (int k = 0; k < 6; k++)
                wpre[k] = *(const bf16x8*)(Wt + (ck + 1) * 12288 + (tid + k * 256) * 8);
        }
        __syncthreads();
#pragma unroll
        for (int kh = 0; kh < 2; kh++) {
            bf16x8 a = *(bf16x8*)(&Xc[(wv * 16 + l16) * 72 + kh * 32 + quad * 8]);
#pragma unroll
            for (int n = 0; n < 12; n++) {
                bf16x8 b = *(bf16x8*)(&Wc[(n * 16 + l16) * 72 + kh * 32 + quad * 8]);
                acc[n] = __builtin_amdgcn_mfma_f32_16x16x32_bf16(a, b, acc[n], 0, 0, 0);
            }
        }
    }

    __syncthreads();
    const int drow = wv * 16 + quad * 4;
#pragma unroll
    for (int n = 0; n < 4; n++) {
#pragma unroll
        for (int r = 0; r < 4; r++) {
            Xs[0][(drow + r) * 72 + n * 16 + l16] = (bf16)(acc[n][r] * SCALE_LOG2E);
            Xs[1][(drow + r) * 72 + n * 16 + l16] = (bf16)acc[n + 4][r];
            Ws[0][(n * 16 + l16) * 72 + drow + r] = (bf16)acc[n + 8][r];
        }
    }
    __syncthreads();
    const int b = row0 >> 11, t0 = row0 & 2047;
    const int srow = tid >> 2, scb = (tid & 3) * 16;
#pragma unroll
    for (int i = 0; i < 2; i++) {
        *(bf16x8*)(Qb + (long)(row0 + srow) * 64 + scb + i * 8) =
            *(bf16x8*)(&Xs[0][srow * 72 + scb + i * 8]);
        *(bf16x8*)(Kb + (long)(row0 + srow) * 64 + scb + i * 8) =
            *(bf16x8*)(&Xs[1][srow * 72 + scb + i * 8]);
        *(bf16x8*)(Vtg + (long)(b * 64 + srow) * 2048 + t0 + scb + i * 8) =
            *(bf16x8*)(&Ws[0][srow * 72 + scb + i * 8]);
    }
}

// ---------------------------------------------------------------------------
// Kernel 2: flash attention, 512 blocks x 256 thr (4 waves), 32 k-iters.
// Single barrier/iter (PV lags S by 1). All tiles [64][64] bf16, 128 B rows,
// XOR-swizzled (tp/tpc). LDS 49152 B:
//   Qs/Ps0 @0 | KsA 2x8192 @8192 | VsA 2x8192 @24576 | Ps1 @40960
//   Om [64][68] f32 overlays @8192 (epilogue only).
// Parity audit unchanged from R7 (all write->cross-wave-read pairs are
// barrier-separated; K commit/read, V commit/read, Ps write/read on
// opposite parities).
// ---------------------------------------------------------------------------
__global__ __launch_bounds__(256) void flash_attn(const bf16* __restrict__ Qb,
                                                  const bf16* __restrict__ Kb,
                                                  const bf16* __restrict__ Vtg,
                                                  float* __restrict__ out) {
    __shared__ __align__(16) char smem[49152];
    bf16* Qs  = (bf16*)smem;                  // [64][64]; Ps0 overlays after hoist
    bf16* Ps0 = Qs;
    bf16* Ps1 = (bf16*)(smem + 40960);

    const int tid = threadIdx.x;
    const int wv = tid >> 6, lane = tid & 63, quad = lane >> 4, l16 = lane & 15;
    // XCD-aware swizzle: keep a batch's K/V resident in one XCD's L2.
    const int i0 = blockIdx.x;
    const int b = (i0 & 7) + 8 * ((i0 >> 3) >> 5);
    const int qt = (i0 >> 3) & 31;

    const bf16* Qg = Qb + (long)(b * 2048 + qt * 64) * 64;
    const bf16* Kg = Kb + (long)b * 2048 * 64;
    const bf16* Vg = Vtg + (long)b * 64 * 2048;

    const int srow = tid >> 2, scb = (tid & 3) * 16;
    // stage Q tile [64][64] (swizzled)
    *(bf16x8*)tp(Qs, srow, scb * 2)      = *(const bf16x8*)(Qg + srow * 64 + scb);
    *(bf16x8*)tp(Qs, srow, scb * 2 + 16) = *(const bf16x8*)(Qg + srow * 64 + scb + 8);

    // prologue loads: K[0] (commit now), K[1] and V[0] (regs for kt=0)
    bf16x8 k0[2], kp[2], vp[2];
#pragma unroll
    for (int i = 0; i < 2; i++) {
        k0[i] = *(const bf16x8*)(Kg + (long)srow * 64 + scb + i * 8);
        kp[i] = *(const bf16x8*)(Kg + (long)(64 + srow) * 64 + scb + i * 8);
        vp[i] = *(const bf16x8*)(Vg + (long)srow * 2048 + scb + i * 8);
    }
    bf16* Ks0 = (bf16*)(smem + 8192);
#pragma unroll
    for (int i = 0; i < 2; i++)
        *(bf16x8*)tp(Ks0, srow, scb * 2 + i * 16) = k0[i];

    f32x4 o[4], ol;
#pragma unroll
    for (int n = 0; n < 4; n++) o[n] = (f32x4){0.f, 0.f, 0.f, 0.f};
    ol = (f32x4){0.f, 0.f, 0.f, 0.f};

    __syncthreads();            // Qs + K[0] staged
    // hoist Q^T b-frags (loop-invariant)
    bf16x8 qb[4][2];
#pragma unroll
    for (int nt = 0; nt < 4; nt++)
#pragma unroll
        for (int kh = 0; kh < 2; kh++)
            qb[nt][kh] = *(bf16x8*)tp(Qs, nt * 16 + l16, kh * 64 + quad * 16);
    __syncthreads();            // all waves hoisted before Ps0 (=Qs) writes

    const bf16 one = (bf16)1.0f;
    const bf16x8 ones = {one, one, one, one, one, one, one, one};

#pragma unroll 2
    for (int kt = 0; kt < 32; kt++) {
        bf16* Kc = (bf16*)(smem + 8192  + (kt & 1) * 8192);        // S src: K[kt]
        bf16* Kn = (bf16*)(smem + 8192  + ((kt + 1) & 1) * 8192);  // commit K[kt+1]
        bf16* Vn = (bf16*)(smem + 24576 + (kt & 1) * 8192);        // commit V[kt]
        bf16* Vp = (bf16*)(smem + 24576 + ((kt + 1) & 1) * 8192);  // PV src: V[kt-1]
        bf16* Pw = (kt & 1) ? Ps1 : Ps0;                           // write Ps[kt]
        bf16* Pr = (kt & 1) ? Ps0 : Ps1;                           // read  Ps[kt-1]

        // commit prefetched tiles (regions not read this iteration)
        if (kt < 31) {
#pragma unroll
            for (int i = 0; i < 2; i++)
                *(bf16x8*)tp(Kn, srow, scb * 2 + i * 16) = kp[i];
        }
#pragma unroll
        for (int i = 0; i < 2; i++)
            *(bf16x8*)tp(Vn, srow, scb * 2 + i * 16) = vp[i];
        // issue next prefetches
        if (kt < 30) {
#pragma unroll
            for (int i = 0; i < 2; i++)
                kp[i] = *(const bf16x8*)(Kg + (long)((kt + 2) * 64 + srow) * 64 + scb + i * 8);
        }
        if (kt < 31) {
#pragma unroll
            for (int i = 0; i < 2; i++)
                vp[i] = *(const bf16x8*)(Vg + (long)srow * 2048 + (kt + 1) * 64 + scb + i * 8);
        }

        // S^T[kt] = K Q^T : wave's key subtile (m=wv), all 4 q-tiles
        f32x4 s[4];
#pragma unroll
        for (int nt = 0; nt < 4; nt++) s[nt] = (f32x4){0.f, 0.f, 0.f, 0.f};
#pragma unroll
        for (int kh = 0; kh < 2; kh++) {
            bf16x8 ka = *(bf16x8*)tp(Kc, wv * 16 + l16, kh * 64 + quad * 16);
#pragma unroll
            for (int nt = 0; nt < 4; nt++)
                s[nt] = __builtin_amdgcn_mfma_f32_16x16x32_bf16(ka, qb[nt][kh], s[nt], 0, 0, 0);
        }
        // p = exp2(s), pack 4 -> b64 store into Ps[kt]
#pragma unroll
        for (int nt = 0; nt < 4; nt++) {
            bf16x4 pp;
#pragma unroll
            for (int r = 0; r < 4; r++)
                pp[r] = (bf16)__builtin_amdgcn_exp2f(s[nt][r]);
            *(bf16x4*)tp(Pw, nt * 16 + l16, wv * 32 + quad * 8) = pp;
        }

        // O^T += V[kt-1]^T Ps[kt-1] : wave's q subtile (n=wv), 4 h-tiles + l
        if (kt) {
#pragma unroll
            for (int kh = 0; kh < 2; kh++) {
                bf16x8 pb = *(bf16x8*)tp(Pr, wv * 16 + l16, kh * 64 + quad * 16);
#pragma unroll
                for (int mt = 0; mt < 4; mt++) {
                    bf16x8 va = *(bf16x8*)tp(Vp, mt * 16 + l16, kh * 64 + quad * 16);
                    o[mt] = __builtin_amdgcn_mfma_f32_16x16x32_bf16(va, pb, o[mt], 0, 0, 0);
                }
                ol = __builtin_amdgcn_mfma_f32_16x16x32_bf16(ones, pb, ol, 0, 0, 0);
            }
        }
        __syncthreads();        // single barrier: publishes K[kt+1],V[kt],Ps[kt]
    }

    // peeled PV[31]: Ps[31] in Ps1, V[31] in VsA parity 1
    {
        bf16* Pr = Ps1;
        bf16* Vp = (bf16*)(smem + 24576 + 8192);
#pragma unroll
        for (int kh = 0; kh < 2; kh++) {
            bf16x8 pb = *(bf16x8*)tp(Pr, wv * 16 + l16, kh * 64 + quad * 16);
#pragma unroll
            for (int mt = 0; mt < 4; mt++) {
                bf16x8 va = *(bf16x8*)tp(Vp, mt * 16 + l16, kh * 64 + quad * 16);
                o[mt] = __builtin_amdgcn_mfma_f32_16x16x32_bf16(va, pb, o[mt], 0, 0, 0);
            }
            ol = __builtin_amdgcn_mfma_f32_16x16x32_bf16(ones, pb, ol, 0, 0, 0);
        }
    }

    // epilogue: every lane holds l(q) in ol[*]; normalize, transpose via LDS
    float inv = 1.0f / ol[0];
    __syncthreads();
    float* Om = (float*)(smem + 8192);        // [64][68] floats (17408 B)
#pragma unroll
    for (int mt = 0; mt < 4; mt++) {
        f32x4 ov;
#pragma unroll
        for (int r = 0; r < 4; r++) ov[r] = o[mt][r] * inv;
        *(f32x4*)(&Om[(wv * 16 + l16) * 68 + mt * 16 + quad * 4]) = ov;
    }
    __syncthreads();
    float* og = out + (long)(b * 2048 + qt * 64 + srow) * 64 + scb;
#pragma unroll
    for (int j = 0; j < 4; j++)
        *(float4*)(og + j * 4) = *(float4*)(&Om[srow * 68 + scb + j * 4]);
}

// ---------------------------------------------------------------------------
extern "C" void kernel_launch(void* const* d_in, const int* in_sizes, int n_in,
                              void* d_out, int out_size, void* d_ws, size_t ws_size,
                              hipStream_t stream) {
    const float* x  = (const float*)d_in[0];
    const float* Wq = (const float*)d_in[1];
    const float* Wk = (const float*)d_in[2];
    const float* Wv = (const float*)d_in[3];
    float* out = (float*)d_out;

    bf16* Qb  = (bf16*)d_ws;           // 32768*64
    bf16* Kb  = Qb + 2097152;
    bf16* Vtg = Kb + 2097152;          // [16][64][2048]
    bf16* Wt  = Vtg + 2097152;         // 6*192*64

    pack_w<<<288, 256, 0, stream>>>(Wq, Wk, Wv, Wt);
    qkv_proj<<<512, 256, 0, stream>>>(x, Wt, Qb, Kb, Vtg);
    flash_attn<<<512, 256, 0, stream>>>(Qb, Kb, Vtg, out);
}